// Round 14
// baseline (2821.116 us; speedup 1.0000x reference)
//
#include <hip/hip_runtime.h>
#include <math.h>

#define N_NODES 20000
#define N_EDGES 1280000
#define NLAYERS 4
#define NTILE (N_EDGES/32)
#define SCHUNK 79    // ceil(N_NODES/256)

typedef short bf16x8 __attribute__((ext_vector_type(8)));
typedef float f32x4  __attribute__((ext_vector_type(4)));
typedef long long i64;
typedef unsigned short us;

// silu via v_rcp_f32 (R13-proven)
__device__ __forceinline__ float silu_f(float x) {
    return x * __builtin_amdgcn_rcpf(1.0f + __expf(-x));
}

__device__ __forceinline__ us f2b(float x) {
    union { float f; unsigned u; } v; v.f = x;
    unsigned r = v.u + 0x7FFF + ((v.u >> 16) & 1);
    return (us)(r >> 16);
}
__device__ __forceinline__ float b2f(us u) {
    union { float f; unsigned u; } v; v.u = ((unsigned)u) << 16;
    return v.f;
}
__device__ __forceinline__ void split2r(float x, us& hi, us& lo) {  // RNE, cold
    hi = f2b(x);
    lo = f2b(x - b2f(hi));
}
// hot-path truncation split
__device__ __forceinline__ void split2f(float x, us& hi, us& lo) {
    union { float f; unsigned u; } v; v.f = x;
    hi = (us)(v.u >> 16);
    union { float f; unsigned u; } h; h.u = v.u & 0xFFFF0000u;
    union { float f; unsigned u; } r; r.f = x - h.f;
    lo = (us)(r.u >> 16);
}

__device__ __forceinline__ bf16x8 ld8(const us* p) {
    bf16x8 a;
    ((i64*)&a)[0] = *(const i64*)p;
    ((i64*)&a)[1] = *(const i64*)(p + 4);
    return a;
}

__device__ __forceinline__ bf16x8 pack8(us h0, us h1, us h2, us h3,
                                        us l0, us l1, us l2, us l3) {
    union { bf16x8 v; unsigned u[4]; } w;
    w.u[0] = (unsigned)h0 | ((unsigned)h1 << 16);
    w.u[1] = (unsigned)h2 | ((unsigned)h3 << 16);
    w.u[2] = (unsigned)l0 | ((unsigned)l1 << 16);
    w.u[3] = (unsigned)l2 | ((unsigned)l3 << 16);
    return w.v;
}

__device__ __forceinline__ void mfma3(f32x4& acc, bf16x8 ahi, bf16x8 alo,
                                      bf16x8 bhi, bf16x8 blo) {
    acc = __builtin_amdgcn_mfma_f32_16x16x32_bf16(ahi, bhi, acc, 0, 0, 0);
    acc = __builtin_amdgcn_mfma_f32_16x16x32_bf16(alo, bhi, acc, 0, 0, 0);
    acc = __builtin_amdgcn_mfma_f32_16x16x32_bf16(ahi, blo, acc, 0, 0, 0);
}

// ---------------- init ----------------
__global__ void k_init(const float* __restrict__ inp,
                       const float* __restrict__ emb_w,
                       const float* __restrict__ emb_b,
                       float* __restrict__ outv,
                       us* __restrict__ hbh, us* __restrict__ hbl) {
    int t = blockIdx.x * blockDim.x + threadIdx.x;
    int n = t >> 6, f = t & 63;
    if (n >= N_NODES) return;
    float vx = inp[n*6+3], vy = inp[n*6+4], vz = inp[n*6+5];
    float sp = sqrtf(vx*vx + vy*vy + vz*vz);
    float hv = sp * emb_w[f] + emb_b[f];
    us hi, lo; split2r(hv, hi, lo);
    hbh[t] = hi; hbl[t] = lo;
    if (f < 6) outv[n*6+f] = inp[n*6+f];
}

// ---------------- CSR build ----------------
__global__ void k_cnt(const int* __restrict__ recv, int* __restrict__ counts) {
    int t = blockIdx.x*256 + threadIdx.x;
    if (t < N_EDGES) atomicAdd(&counts[recv[t]], 1);
}

__global__ void k_scan(const int* __restrict__ counts, int* __restrict__ rowstart,
                       int* __restrict__ cursor, int* __restrict__ tile2node) {
    __shared__ int buf[256];
    const int tid = threadIdx.x;
    const int lo = tid*SCHUNK;
    const int hi = (lo + SCHUNK < N_NODES) ? lo + SCHUNK : N_NODES;
    int s = 0;
    for (int i = lo; i < hi; ++i) s += counts[i];
    buf[tid] = s;
    __syncthreads();
    for (int off = 1; off < 256; off <<= 1) {
        int v = (tid >= off) ? buf[tid-off] : 0;
        __syncthreads();
        buf[tid] += v;
        __syncthreads();
    }
    int run = buf[tid] - s;
    for (int i = lo; i < hi; ++i) {
        rowstart[i] = run; cursor[i] = run;
        const int c = counts[i];
        for (int t = (run + 31) >> 5; t*32 < run + c; ++t) tile2node[t] = i;
        run += c;
    }
    if (tid < 20) rowstart[N_NODES + tid] = N_EDGES;
}

__global__ void k_scatter(const int* __restrict__ send, const int* __restrict__ recv,
                          int* __restrict__ cursor, us* __restrict__ sp16) {
    int t = blockIdx.x*256 + threadIdx.x;
    if (t < N_EDGES) {
        int p = atomicAdd(&cursor[recv[t]], 1);
        sp16[p] = (us)send[t];
    }
}

// ---------------- weight prep ----------------
// w1t: [n=outfeat 64][k=infeat 128] hi/lo (GEMM1 A-operand, K=32 frags).
// w2a/cwa: virtual-K A-mats for the operand-swapped GEMM2/3:
//   A[m=outfeat][v], v = kt*32 + q*8 + j; f = 16*kt + 4*q + (j&3)
//   a1[v] = hi(W[f][m]) (j<4 and j>=4 both)   -> pairs with B=[t1hi|t1lo]: (hi+lo)*Whi
//   a2[v] = lo(W[f][m])                        -> hi*Wlo + lo*Wlo
__global__ void k_prepw(const float* __restrict__ ew1, const float* __restrict__ ew2,
                        const float* __restrict__ cw1,
                        us* __restrict__ w1th, us* __restrict__ w1tl,
                        us* __restrict__ w2a1, us* __restrict__ w2a2,
                        us* __restrict__ cwa1, us* __restrict__ cwa2) {
    int t = blockIdx.x*256 + threadIdx.x;   // 4 * 24576 total
    int l = t / 24576;
    int r = t % 24576;
    us hi, lo;
    if (r < 8192) {                          // w1t: n = r>>7, k = r&127
        int n = r >> 7, k = r & 127;
        split2r(ew1[l*129*64 + k*64 + n], hi, lo);
        w1th[l*8192 + r] = hi; w1tl[l*8192 + r] = lo;
    } else if (r < 16384) {
        int rr = r - 8192;
        int m = rr >> 7, v = rr & 127;
        int kt = v >> 5, qq = (v >> 3) & 3, j = v & 7;
        int f = 16*kt + 4*qq + (j & 3);
        split2r(ew2[l*4096 + f*64 + m], hi, lo);
        w2a1[l*8192 + rr] = hi; w2a2[l*8192 + rr] = lo;
    } else {
        int rr = r - 16384;
        int m = rr >> 7, v = rr & 127;
        int kt = v >> 5, qq = (v >> 3) & 3, j = v & 7;
        int f = 16*kt + 4*qq + (j & 3);
        split2r(cw1[l*4096 + f*64 + m], hi, lo);
        cwa1[l*8192 + rr] = hi; cwa2[l*8192 + rr] = lo;
    }
}

// ---------------- recv-half precompute (layer 0; fused into k_node after) ----------------
__launch_bounds__(256, 4)
__global__ void k_recv(const us* __restrict__ hbh, const us* __restrict__ hbl,
                       const float* __restrict__ ew1,
                       const float* __restrict__ eb1,
                       float* __restrict__ R) {
    __shared__ float hs[4][64];
    const int tid = threadIdx.x;
    const int nn = tid >> 6, f = tid & 63;
    const int n = blockIdx.x*4 + nn;
    hs[nn][f] = b2f(hbh[(size_t)n*64+f]) + b2f(hbl[(size_t)n*64+f]);
    __syncthreads();
    float p0 = 0.f, p1 = 0.f, p2 = 0.f, p3 = 0.f;
    for (int k = 0; k < 64; k += 4) {
        p0 += hs[nn][k+0] * ew1[(64+k+0)*64 + f];
        p1 += hs[nn][k+1] * ew1[(64+k+1)*64 + f];
        p2 += hs[nn][k+2] * ew1[(64+k+2)*64 + f];
        p3 += hs[nn][k+3] * ew1[(64+k+3)*64 + f];
    }
    R[(size_t)n*64+f] = eb1[f] + (p0+p1) + (p2+p3);
}

// ---------------- fused MFMA edge kernel: operand-swapped, zero LDS ----------------
// GEMM1: D = W1^T * h  (A=weights m=outfeat, B=h n=edge). Output lands with edge
// on lane index, features on quad*4+reg — directly the B-operand layout for the
// next GEMM. GEMM2/3 chain in-register via virtual-K A-mats; no LDS, no barriers.
__launch_bounds__(128, 4)
__global__ void k_edge(const us* __restrict__ sp16, const int* __restrict__ rowstart,
                       const int* __restrict__ tile2node,
                       const us* __restrict__ hbh, const us* __restrict__ hbl,
                       const float* __restrict__ outv,
                       const float* __restrict__ R,
                       const us* __restrict__ w1th, const us* __restrict__ w1tl,
                       const us* __restrict__ w2a1, const us* __restrict__ w2a2,
                       const us* __restrict__ cwa1, const us* __restrict__ cwa2,
                       const float* __restrict__ ew1,
                       const float* __restrict__ eb2, const float* __restrict__ cb1,
                       const float* __restrict__ cwo,
                       float* __restrict__ aggs, float* __restrict__ aggm) {
    const int tid  = threadIdx.x;
    const int wid  = tid >> 6;
    const int lane = tid & 63;
    const int q    = lane >> 4;
    const int l15  = lane & 15;
    const int q8   = q*8, qb = q*4;
    const int wbase = blockIdx.x*64 + wid*32;
    const int wtile = blockIdx.x*2 + wid;

    const int e0 = wbase + l15, e1 = e0 + 16;
    const int s0 = sp16[e0], s1 = sp16[e1];

    const int t2n = tile2node[wtile];
    const int wv = rowstart[t2n + 1 + l15];
    int seg0 = 0, seg1 = 0;
    #pragma unroll
    for (int i = 0; i < 16; ++i) {
        const int wi = __shfl(wv, i);
        seg0 += (e0 >= wi);
        seg1 += (e1 >= wi);
    }
    const int r0 = t2n + seg0, r1 = t2n + seg1;
    const int segA = __shfl(seg0, 0);
    const int segB = __shfl(seg1, 15);

    // per-lane edge geometry (lane = its own edge now, everywhere)
    const float cdx0 = outv[s0*6+0]-outv[r0*6+0], cdy0 = outv[s0*6+1]-outv[r0*6+1], cdz0 = outv[s0*6+2]-outv[r0*6+2];
    const float cdx1 = outv[s1*6+0]-outv[r1*6+0], cdy1 = outv[s1*6+1]-outv[r1*6+1], cdz1 = outv[s1*6+2]-outv[r1*6+2];
    const float rad0 = cdx0*cdx0+cdy0*cdy0+cdz0*cdz0;
    const float rad1 = cdx1*cdx1+cdy1*cdy1+cdz1*cdz1;

    // per-lane feature-column constants: feature = 16t + 4q + r  -> float4 loads
    f32x4 wl4[4], eb24[4], cb14[4], cwo4[4];
    #pragma unroll
    for (int t = 0; t < 4; ++t) {
        const int cb = 16*t + qb;
        wl4[t]  = *(const f32x4*)&ew1[8192 + cb];   // radial row of W1
        eb24[t] = *(const f32x4*)&eb2[cb];
        cb14[t] = *(const f32x4*)&cb1[cb];
        cwo4[t] = *(const f32x4*)&cwo[cb];
    }

    f32x4 acc[2][4];
    // acc init from R (recv half + b1): feature layout matches float4 rows
    if (segB == segA) {
        const int rn = t2n + segA;
        #pragma unroll
        for (int t = 0; t < 4; ++t) {
            const f32x4 rv = *(const f32x4*)&R[(size_t)rn*64 + 16*t + qb];
            acc[0][t] = rv; acc[1][t] = rv;
        }
    } else {
        const size_t o0 = (size_t)(t2n + seg0)*64;
        const size_t o1 = (size_t)(t2n + seg1)*64;
        #pragma unroll
        for (int t = 0; t < 4; ++t) {
            acc[0][t] = *(const f32x4*)&R[o0 + 16*t + qb];
            acc[1][t] = *(const f32x4*)&R[o1 + 16*t + qb];
        }
    }

    // ---- GEMM1 (send half, K=64): A = W1^T frags, B = h frags ----
    #pragma unroll
    for (int kc = 0; kc < 2; ++kc) {
        const int off = kc*32 + q8;
        bf16x8 b0h = ld8(hbh + (size_t)s0*64 + off), b0l = ld8(hbl + (size_t)s0*64 + off);
        bf16x8 b1h = ld8(hbh + (size_t)s1*64 + off), b1l = ld8(hbl + (size_t)s1*64 + off);
        #pragma unroll
        for (int t = 0; t < 4; ++t) {
            const int wo = (16*t + l15)*128 + off;
            bf16x8 ah = ld8(w1th + wo), al = ld8(w1tl + wo);
            mfma3(acc[0][t], ah, al, b0h, b0l);
            mfma3(acc[1][t], ah, al, b1h, b1l);
        }
    }

    // radial column (fp32 exact), per-lane rad
    #pragma unroll
    for (int t = 0; t < 4; ++t)
        #pragma unroll
        for (int r = 0; r < 4; ++r) {
            acc[0][t][r] += rad0 * wl4[t][r];
            acc[1][t][r] += rad1 * wl4[t][r];
        }

    // ---- GEMM2: t1 @ W2, in-register (B = [t1hi|t1lo] packs, A = virtual-K) ----
    f32x4 acc2[2][4];
    #pragma unroll
    for (int mu = 0; mu < 2; ++mu)
        #pragma unroll
        for (int t = 0; t < 4; ++t) acc2[mu][t] = (f32x4){0.f,0.f,0.f,0.f};
    #pragma unroll
    for (int mu = 0; mu < 2; ++mu)
        #pragma unroll
        for (int kt = 0; kt < 4; ++kt) {
            us h0,h1,h2,h3,l0,l1,l2,l3;
            split2f(silu_f(acc[mu][kt][0]), h0, l0);
            split2f(silu_f(acc[mu][kt][1]), h1, l1);
            split2f(silu_f(acc[mu][kt][2]), h2, l2);
            split2f(silu_f(acc[mu][kt][3]), h3, l3);
            const bf16x8 B = pack8(h0,h1,h2,h3, l0,l1,l2,l3);
            #pragma unroll
            for (int t = 0; t < 4; ++t) {
                const int wo = (16*t + l15)*128 + kt*32 + q8;
                bf16x8 a1 = ld8(w2a1 + wo), a2 = ld8(w2a2 + wo);
                acc2[mu][t] = __builtin_amdgcn_mfma_f32_16x16x32_bf16(a1, B, acc2[mu][t], 0, 0, 0);
                acc2[mu][t] = __builtin_amdgcn_mfma_f32_16x16x32_bf16(a2, B, acc2[mu][t], 0, 0, 0);
            }
        }

    // ef = silu(acc2 + b2), fp32 regs for scatter
    f32x4 ef[2][4];
    #pragma unroll
    for (int mu = 0; mu < 2; ++mu)
        #pragma unroll
        for (int t = 0; t < 4; ++t)
            #pragma unroll
            for (int r = 0; r < 4; ++r)
                ef[mu][t][r] = silu_f(acc2[mu][t][r] + eb24[t][r]);

    // ---- GEMM3: ef @ CW1, in-register ----
    f32x4 acc3[2][4];
    #pragma unroll
    for (int mu = 0; mu < 2; ++mu)
        #pragma unroll
        for (int t = 0; t < 4; ++t) acc3[mu][t] = (f32x4){0.f,0.f,0.f,0.f};
    #pragma unroll
    for (int mu = 0; mu < 2; ++mu)
        #pragma unroll
        for (int kt = 0; kt < 4; ++kt) {
            us h0,h1,h2,h3,l0,l1,l2,l3;
            split2f(ef[mu][kt][0], h0, l0);
            split2f(ef[mu][kt][1], h1, l1);
            split2f(ef[mu][kt][2], h2, l2);
            split2f(ef[mu][kt][3], h3, l3);
            const bf16x8 B = pack8(h0,h1,h2,h3, l0,l1,l2,l3);
            #pragma unroll
            for (int t = 0; t < 4; ++t) {
                const int wo = (16*t + l15)*128 + kt*32 + q8;
                bf16x8 a1 = ld8(cwa1 + wo), a2 = ld8(cwa2 + wo);
                acc3[mu][t] = __builtin_amdgcn_mfma_f32_16x16x32_bf16(a1, B, acc3[mu][t], 0, 0, 0);
                acc3[mu][t] = __builtin_amdgcn_mfma_f32_16x16x32_bf16(a2, B, acc3[mu][t], 0, 0, 0);
            }
        }

    // ---- GEMM4: cm per lane (own edge), reduce partials across quads ----
    float cmv0 = 0.f, cmv1 = 0.f;
    #pragma unroll
    for (int t = 0; t < 4; ++t)
        #pragma unroll
        for (int r = 0; r < 4; ++r) {
            cmv0 += silu_f(acc3[0][t][r] + cb14[t][r]) * cwo4[t][r];
            cmv1 += silu_f(acc3[1][t][r] + cb14[t][r]) * cwo4[t][r];
        }
    cmv0 += __shfl_xor(cmv0, 16); cmv0 += __shfl_xor(cmv0, 32);
    cmv1 += __shfl_xor(cmv1, 16); cmv1 += __shfl_xor(cmv1, 32);

    // trans per lane (own edge)
    float tv[2][3];
    tv[0][0] = fminf(fmaxf(cdx0*cmv0, -100.f), 100.f);
    tv[0][1] = fminf(fmaxf(cdy0*cmv0, -100.f), 100.f);
    tv[0][2] = fminf(fmaxf(cdz0*cmv0, -100.f), 100.f);
    tv[1][0] = fminf(fmaxf(cdx1*cmv1, -100.f), 100.f);
    tv[1][1] = fminf(fmaxf(cdy1*cmv1, -100.f), 100.f);
    tv[1][2] = fminf(fmaxf(cdz1*cmv1, -100.f), 100.f);

    if (segB == segA) {
        // single-node wave: reduce over 16 lanes (edges) per quad
        f32x4 v[4];
        #pragma unroll
        for (int t = 0; t < 4; ++t) {
            v[t] = ef[0][t] + ef[1][t];
            #pragma unroll
            for (int r = 0; r < 4; ++r) {
                float x = v[t][r];
                x += __shfl_xor(x, 1); x += __shfl_xor(x, 2);
                x += __shfl_xor(x, 4); x += __shfl_xor(x, 8);
                v[t][r] = x;
            }
        }
        float t0 = tv[0][0]+tv[1][0], t1 = tv[0][1]+tv[1][1], t2 = tv[0][2]+tv[1][2];
        t0 += __shfl_xor(t0,1); t0 += __shfl_xor(t0,2); t0 += __shfl_xor(t0,4); t0 += __shfl_xor(t0,8);
        t1 += __shfl_xor(t1,1); t1 += __shfl_xor(t1,2); t1 += __shfl_xor(t1,4); t1 += __shfl_xor(t1,8);
        t2 += __shfl_xor(t2,1); t2 += __shfl_xor(t2,2); t2 += __shfl_xor(t2,4); t2 += __shfl_xor(t2,8);
        const int rn = t2n + segA;
        if (l15 == 0) {
            #pragma unroll
            for (int t = 0; t < 4; ++t)
                #pragma unroll
                for (int r = 0; r < 4; ++r)
                    atomicAdd(&aggs[(size_t)rn*64 + 16*t + qb + r], v[t][r]);
        }
        if (q == 0 && l15 < 3) {
            const float w = (l15 == 0) ? t0 : (l15 == 1) ? t1 : t2;
            atomicAdd(&aggm[rn*3 + l15], w);
        }
    } else if (segB == segA + 1) {
        const bool A0 = (seg0 == segA), A1 = (seg1 == segA);
        f32x4 vA[4], vB[4];
        #pragma unroll
        for (int t = 0; t < 4; ++t) {
            #pragma unroll
            for (int r = 0; r < 4; ++r) {
                const float a = (A0 ? ef[0][t][r] : 0.f) + (A1 ? ef[1][t][r] : 0.f);
                const float b = (A0 ? 0.f : ef[0][t][r]) + (A1 ? 0.f : ef[1][t][r]);
                float xa = a, xb = b;
                xa += __shfl_xor(xa,1); xa += __shfl_xor(xa,2); xa += __shfl_xor(xa,4); xa += __shfl_xor(xa,8);
                xb += __shfl_xor(xb,1); xb += __shfl_xor(xb,2); xb += __shfl_xor(xb,4); xb += __shfl_xor(xb,8);
                vA[t][r] = xa; vB[t][r] = xb;
            }
        }
        float trA[3], trB[3];
        #pragma unroll
        for (int c = 0; c < 3; ++c) {
            float a = (A0 ? tv[0][c] : 0.f) + (A1 ? tv[1][c] : 0.f);
            float b = (A0 ? 0.f : tv[0][c]) + (A1 ? 0.f : tv[1][c]);
            a += __shfl_xor(a,1); a += __shfl_xor(a,2); a += __shfl_xor(a,4); a += __shfl_xor(a,8);
            b += __shfl_xor(b,1); b += __shfl_xor(b,2); b += __shfl_xor(b,4); b += __shfl_xor(b,8);
            trA[c] = a; trB[c] = b;
        }
        const int rnA = t2n + segA, rnB = rnA + 1;
        if (l15 == 0) {
            #pragma unroll
            for (int t = 0; t < 4; ++t)
                #pragma unroll
                for (int r = 0; r < 4; ++r) {
                    atomicAdd(&aggs[(size_t)rnA*64 + 16*t + qb + r], vA[t][r]);
                    atomicAdd(&aggs[(size_t)rnB*64 + 16*t + qb + r], vB[t][r]);
                }
        }
        if (q == 0 && l15 < 3) {
            const float wa = (l15 == 0) ? trA[0] : (l15 == 1) ? trA[1] : trA[2];
            const float wb = (l15 == 0) ? trB[0] : (l15 == 1) ? trB[1] : trB[2];
            atomicAdd(&aggm[rnA*3 + l15], wa);
            atomicAdd(&aggm[rnB*3 + l15], wb);
        }
    } else {
        // general (rare): per-lane writes; quads cover disjoint features
        const int n0 = t2n + seg0, n1 = t2n + seg1;
        #pragma unroll
        for (int t = 0; t < 4; ++t)
            #pragma unroll
            for (int r = 0; r < 4; ++r) {
                atomicAdd(&aggs[(size_t)n0*64 + 16*t + qb + r], ef[0][t][r]);
                atomicAdd(&aggs[(size_t)n1*64 + 16*t + qb + r], ef[1][t][r]);
            }
        if (q == 0) {
            #pragma unroll
            for (int c = 0; c < 3; ++c) {
                atomicAdd(&aggm[n0*3 + c], tv[0][c]);
                atomicAdd(&aggm[n1*3 + c], tv[1][c]);
            }
        }
    }
}

// ---------------- node kernel: 4-way ILP GEMVs + fused next-layer R ----------------
__launch_bounds__(256, 4)
__global__ void k_node(float* __restrict__ aggs, float* __restrict__ aggm,
                       const int* __restrict__ rowstart,
                       const float* __restrict__ VW1, const float* __restrict__ vb1,
                       const float* __restrict__ VW2, const float* __restrict__ vb2,
                       const float* __restrict__ NW1, const float* __restrict__ nb1,
                       const float* __restrict__ NW2, const float* __restrict__ nb2,
                       float* __restrict__ outv,
                       us* __restrict__ hbh, us* __restrict__ hbl,
                       const float* __restrict__ EW1n,
                       const float* __restrict__ eb1n,
                       float* __restrict__ R, int doR) {
    __shared__ float hs[4][64], as[4][64], tt[4][64];
    const int tid = threadIdx.x;
    const int nn = tid >> 6, f = tid & 63;
    const int n = blockIdx.x*4 + nn;
    float hv = b2f(hbh[n*64+f]) + b2f(hbl[n*64+f]);
    hs[nn][f] = hv;
    as[nn][f] = aggs[n*64+f];
    aggs[n*64+f] = 0.f;
    __syncthreads();

    float p0, p1, p2, p3;
    p0 = p1 = p2 = p3 = 0.f;
    for (int k = 0; k < 64; k += 4) {
        p0 += hs[nn][k+0] * VW1[(k+0)*64+f];
        p1 += hs[nn][k+1] * VW1[(k+1)*64+f];
        p2 += hs[nn][k+2] * VW1[(k+2)*64+f];
        p3 += hs[nn][k+3] * VW1[(k+3)*64+f];
    }
    float a1 = vb1[f] + (p0+p1) + (p2+p3);
    float p = silu_f(a1) * VW2[f];
    #pragma unroll
    for (int o = 32; o > 0; o >>= 1) p += __shfl_down(p, o);
    float vgate = __shfl(p, 0) + vb2[0];

    if (f < 3) {
        float icnt = 1.0f / fmaxf((float)(rowstart[n+1] - rowstart[n]), 1.0f);
        float nv = aggm[n*3+f]*icnt + vgate*outv[n*6+3+f];
        aggm[n*3+f] = 0.f;
        outv[n*6+3+f] = nv;
        outv[n*6+f]  += nv;
    }

    p0 = p1 = p2 = p3 = 0.f;
    for (int k = 0; k < 64; k += 4) {
        p0 += hs[nn][k+0]*NW1[(k+0)*64+f] + as[nn][k+0]*NW1[(64+k+0)*64+f];
        p1 += hs[nn][k+1]*NW1[(k+1)*64+f] + as[nn][k+1]*NW1[(64+k+1)*64+f];
        p2 += hs[nn][k+2]*NW1[(k+2)*64+f] + as[nn][k+2]*NW1[(64+k+2)*64+f];
        p3 += hs[nn][k+3]*NW1[(k+3)*64+f] + as[nn][k+3]*NW1[(64+k+3)*64+f];
    }
    float b = nb1[f] + (p0+p1) + (p2+p3);
    __syncthreads();
    tt[nn][f] = silu_f(b);
    __syncthreads();
    p0 = p1 = p2 = p3 = 0.f;
    for (int k = 0; k < 64; k += 4) {
        p0 += tt[nn][k+0]*NW2[(k+0)*64+f];
        p1 += tt[nn][k+1]*NW2[(k+1)*64+f];
        p2 += tt[nn][k+2]*NW2[(k+2)*64+f];
        p3 += tt[nn][k+3]*NW2[(k+3)*64+f];
    }
    float o = nb2[f] + hv + (p0+p1) + (p2+p3);
    us hi, lo; split2r(o, hi, lo);
    hbh[n*64+f] = hi; hbl[n*64+f] = lo;

    if (doR) {
        hs[nn][f] = o;
        __syncthreads();
        p0 = p1 = p2 = p3 = 0.f;
        for (int k = 0; k < 64; k += 4) {
            p0 += hs[nn][k+0] * EW1n[(64+k+0)*64 + f];
            p1 += hs[nn][k+1] * EW1n[(64+k+1)*64 + f];
            p2 += hs[nn][k+2] * EW1n[(64+k+2)*64 + f];
            p3 += hs[nn][k+3] * EW1n[(64+k+3)*64 + f];
        }
        R[(size_t)n*64+f] = eb1n[f] + (p0+p1) + (p2+p3);
    }
}

extern "C" void kernel_launch(void* const* d_in, const int* in_sizes, int n_in,
                              void* d_out, int out_size, void* d_ws, size_t ws_size,
                              hipStream_t stream) {
    const float* inp   = (const float*)d_in[0];
    const int*   send  = (const int*)d_in[2];
    const int*   recv  = (const int*)d_in[3];
    const float* emb_w = (const float*)d_in[4];
    const float* emb_b = (const float*)d_in[5];
    const float* ew1   = (const float*)d_in[6];
    const float* eb1   = (const float*)d_in[7];
    const float* ew2   = (const float*)d_in[8];
    const float* eb2   = (const float*)d_in[9];
    const float* nw1   = (const float*)d_in[10];
    const float* nb1   = (const float*)d_in[11];
    const float* nw2   = (const float*)d_in[12];
    const float* nb2   = (const float*)d_in[13];
    const float* cw1   = (const float*)d_in[14];
    const float* cb1   = (const float*)d_in[15];
    const float* cwo   = (const float*)d_in[16];
    const float* vw1   = (const float*)d_in[17];
    const float* vb1   = (const float*)d_in[18];
    const float* vw2   = (const float*)d_in[19];
    const float* vb2   = (const float*)d_in[20];

    float* outv = (float*)d_out;

    // ws layout — ~18.79 MB (R12 proved >= 18.66)
    float* ws        = (float*)d_ws;
    float* aggs      = ws;
    float* aggm      = aggs + (size_t)N_NODES*64;
    int*   rowstart  = (int*)(aggm + N_NODES*3);
    int*   tile2node = rowstart + (N_NODES+20);
    us*    hbh       = (us*)(tile2node + NTILE);
    us*    hbl       = hbh + (size_t)N_NODES*64;
    us*    sp16      = hbl + (size_t)N_NODES*64;
    us*    w1th      = sp16 + N_EDGES;               // 4*8192
    us*    w1tl      = w1th + 4*8192;
    us*    w2a1      = w1tl + 4*8192;                // 4*8192 each
    us*    w2a2      = w2a1 + 4*8192;
    us*    cwa1      = w2a2 + 4*8192;
    us*    cwa2      = cwa1 + 4*8192;
    float* R         = (float*)(cwa2 + 4*8192);
    int*   counts    = (int*)aggs;
    int*   cursor    = counts + N_NODES;

    hipMemsetAsync(counts, 0, N_NODES*sizeof(int), stream);
    k_init<<<(N_NODES*64)/256, 256, 0, stream>>>(inp, emb_w, emb_b, outv, hbh, hbl);
    k_cnt<<<(N_EDGES+255)/256, 256, 0, stream>>>(recv, counts);
    k_scan<<<1, 256, 0, stream>>>(counts, rowstart, cursor, tile2node);
    k_scatter<<<(N_EDGES+255)/256, 256, 0, stream>>>(send, recv, cursor, sp16);
    k_prepw<<<384, 256, 0, stream>>>(ew1, ew2, cw1, w1th, w1tl, w2a1, w2a2, cwa1, cwa2);
    hipMemsetAsync(aggs, 0, (size_t)N_NODES*67*sizeof(float), stream);
    k_recv<<<N_NODES/4, 256, 0, stream>>>(hbh, hbl, ew1, eb1, R);

    for (int l = 0; l < NLAYERS; ++l) {
        k_edge<<<N_EDGES/64, 128, 0, stream>>>(sp16, rowstart, tile2node, hbh, hbl, outv, R,
            w1th + l*8192, w1tl + l*8192,
            w2a1 + l*8192, w2a2 + l*8192,
            cwa1 + l*8192, cwa2 + l*8192,
            ew1 + (size_t)l*129*64, eb2 + l*64,
            cb1 + l*64, cwo + l*64,
            aggs, aggm);
        const int doR = (l < NLAYERS-1);
        k_node<<<N_NODES/4, 256, 0, stream>>>(aggs, aggm, rowstart,
            vw1 + (size_t)l*64*64, vb1 + l*64, vw2 + l*64, vb2 + l,
            nw1 + (size_t)l*128*64, nb1 + l*64,
            nw2 + (size_t)l*64*64,  nb2 + l*64,
            outv, hbh, hbl,
            ew1 + (size_t)(l+1 < NLAYERS ? l+1 : l)*129*64,
            eb1 + (l+1 < NLAYERS ? l+1 : l)*64,
            R, doR);
    }
}

// Round 15
// 1692.185 us; speedup vs baseline: 1.6671x; 1.6671x over previous
//
#include <hip/hip_runtime.h>
#include <math.h>

#define N_NODES 20000
#define N_EDGES 1280000
#define NLAYERS 4
#define NTILE (N_EDGES/32)
#define TSTRIDE 68   // bf16 elements per LDS tile row (proven 0-conflict)
#define SCHUNK 79    // ceil(N_NODES/256)

typedef short bf16x8 __attribute__((ext_vector_type(8)));
typedef float f32x4  __attribute__((ext_vector_type(4)));
typedef long long i64;
typedef unsigned short us;

// silu via v_rcp_f32 (R13-proven)
__device__ __forceinline__ float silu_f(float x) {
    return x * __builtin_amdgcn_rcpf(1.0f + __expf(-x));
}

__device__ __forceinline__ us f2b(float x) {
    union { float f; unsigned u; } v; v.f = x;
    unsigned r = v.u + 0x7FFF + ((v.u >> 16) & 1);
    return (us)(r >> 16);
}
__device__ __forceinline__ float b2f(us u) {
    union { float f; unsigned u; } v; v.u = ((unsigned)u) << 16;
    return v.f;
}
__device__ __forceinline__ void split2r(float x, us& hi, us& lo) {  // RNE, cold
    hi = f2b(x);
    lo = f2b(x - b2f(hi));
}
// hot-path truncation split: 4 VALU, residual ~2^-16 rel
__device__ __forceinline__ void split2f(float x, us& hi, us& lo) {
    union { float f; unsigned u; } v; v.f = x;
    hi = (us)(v.u >> 16);
    union { float f; unsigned u; } h; h.u = v.u & 0xFFFF0000u;
    union { float f; unsigned u; } r; r.f = x - h.f;
    lo = (us)(r.u >> 16);
}

__device__ __forceinline__ bf16x8 ld8(const us* p) {
    bf16x8 a;
    ((i64*)&a)[0] = *(const i64*)p;
    ((i64*)&a)[1] = *(const i64*)(p + 4);
    return a;
}

__device__ __forceinline__ void mfma3(f32x4& acc, bf16x8 ahi, bf16x8 alo,
                                      bf16x8 bhi, bf16x8 blo) {
    acc = __builtin_amdgcn_mfma_f32_16x16x32_bf16(ahi, bhi, acc, 0, 0, 0);
    acc = __builtin_amdgcn_mfma_f32_16x16x32_bf16(alo, bhi, acc, 0, 0, 0);
    acc = __builtin_amdgcn_mfma_f32_16x16x32_bf16(ahi, blo, acc, 0, 0, 0);
}

// ---------------- init ----------------
__global__ void k_init(const float* __restrict__ inp,
                       const float* __restrict__ emb_w,
                       const float* __restrict__ emb_b,
                       float* __restrict__ outv,
                       us* __restrict__ hbh, us* __restrict__ hbl) {
    int t = blockIdx.x * blockDim.x + threadIdx.x;
    int n = t >> 6, f = t & 63;
    if (n >= N_NODES) return;
    float vx = inp[n*6+3], vy = inp[n*6+4], vz = inp[n*6+5];
    float sp = sqrtf(vx*vx + vy*vy + vz*vz);
    float hv = sp * emb_w[f] + emb_b[f];
    us hi, lo; split2r(hv, hi, lo);
    hbh[t] = hi; hbl[t] = lo;
    if (f < 6) outv[n*6+f] = inp[n*6+f];
}

// ---------------- CSR build ----------------
__global__ void k_cnt(const int* __restrict__ recv, int* __restrict__ counts) {
    int t = blockIdx.x*256 + threadIdx.x;
    if (t < N_EDGES) atomicAdd(&counts[recv[t]], 1);
}

__global__ void k_scan(const int* __restrict__ counts, int* __restrict__ rowstart,
                       int* __restrict__ cursor, int* __restrict__ tile2node) {
    __shared__ int buf[256];
    const int tid = threadIdx.x;
    const int lo = tid*SCHUNK;
    const int hi = (lo + SCHUNK < N_NODES) ? lo + SCHUNK : N_NODES;
    int s = 0;
    for (int i = lo; i < hi; ++i) s += counts[i];
    buf[tid] = s;
    __syncthreads();
    for (int off = 1; off < 256; off <<= 1) {
        int v = (tid >= off) ? buf[tid-off] : 0;
        __syncthreads();
        buf[tid] += v;
        __syncthreads();
    }
    int run = buf[tid] - s;
    for (int i = lo; i < hi; ++i) {
        rowstart[i] = run; cursor[i] = run;
        const int c = counts[i];
        for (int t = (run + 31) >> 5; t*32 < run + c; ++t) tile2node[t] = i;
        run += c;
    }
    if (tid < 20) rowstart[N_NODES + tid] = N_EDGES;
}

__global__ void k_scatter(const int* __restrict__ send, const int* __restrict__ recv,
                          int* __restrict__ cursor, us* __restrict__ sp16) {
    int t = blockIdx.x*256 + threadIdx.x;
    if (t < N_EDGES) {
        int p = atomicAdd(&cursor[recv[t]], 1);
        sp16[p] = (us)send[t];
    }
}

// ---------------- weight prep (R13 layout) ----------------
__global__ void k_prepw(const float* __restrict__ ew1, const float* __restrict__ ew2,
                        const float* __restrict__ cw1,
                        us* __restrict__ w1th, us* __restrict__ w1tl,
                        us* __restrict__ w2th, us* __restrict__ w2tl,
                        us* __restrict__ cw1th, us* __restrict__ cw1tl) {
    int t = blockIdx.x*256 + threadIdx.x;
    int l = t >> 14;
    int r = t & 16383;
    us hi, lo;
    if (r < 8192) {
        int n = r >> 7, k = r & 127;
        split2r(ew1[l*129*64 + k*64 + n], hi, lo);
        w1th[l*8192 + r] = hi; w1tl[l*8192 + r] = lo;
    } else if (r < 12288) {
        int rr = r - 8192; int n = rr >> 6, k = rr & 63;
        split2r(ew2[l*4096 + k*64 + n], hi, lo);
        w2th[l*4096 + n*64 + k] = hi; w2tl[l*4096 + n*64 + k] = lo;
    } else {
        int rr = r - 12288; int n = rr >> 6, k = rr & 63;
        split2r(cw1[l*4096 + k*64 + n], hi, lo);
        cw1th[l*4096 + n*64 + k] = hi; cw1tl[l*4096 + n*64 + k] = lo;
    }
}

// ---------------- recv-half precompute (layer 0; fused into k_node after) ----------------
__launch_bounds__(256, 4)
__global__ void k_recv(const us* __restrict__ hbh, const us* __restrict__ hbl,
                       const float* __restrict__ ew1,
                       const float* __restrict__ eb1,
                       float* __restrict__ R) {
    __shared__ float hs[4][64];
    const int tid = threadIdx.x;
    const int nn = tid >> 6, f = tid & 63;
    const int n = blockIdx.x*4 + nn;
    hs[nn][f] = b2f(hbh[(size_t)n*64+f]) + b2f(hbl[(size_t)n*64+f]);
    __syncthreads();
    float p0 = 0.f, p1 = 0.f, p2 = 0.f, p3 = 0.f;
    for (int k = 0; k < 64; k += 4) {
        p0 += hs[nn][k+0] * ew1[(64+k+0)*64 + f];
        p1 += hs[nn][k+1] * ew1[(64+k+1)*64 + f];
        p2 += hs[nn][k+2] * ew1[(64+k+2)*64 + f];
        p3 += hs[nn][k+3] * ew1[(64+k+3)*64 + f];
    }
    R[(size_t)n*64+f] = eb1[f] + (p0+p1) + (p2+p3);
}

// ---------------- fused MFMA edge kernel (R13-proven, 307 us/layer) ----------------
__launch_bounds__(128, 4)
__global__ void k_edge(const us* __restrict__ sp16, const int* __restrict__ rowstart,
                       const int* __restrict__ tile2node,
                       const us* __restrict__ hbh, const us* __restrict__ hbl,
                       const float* __restrict__ outv,
                       const float* __restrict__ R,
                       const us* __restrict__ w1th, const us* __restrict__ w1tl,
                       const us* __restrict__ w2th, const us* __restrict__ w2tl,
                       const us* __restrict__ cw1th, const us* __restrict__ cw1tl,
                       const float* __restrict__ ew1,
                       const float* __restrict__ eb2, const float* __restrict__ cb1,
                       const float* __restrict__ cwo,
                       float* __restrict__ aggs, float* __restrict__ aggm) {
    __shared__ us tileh[2][32*TSTRIDE];
    __shared__ us tilel[2][32*TSTRIDE];

    const int tid  = threadIdx.x;
    const int wid  = tid >> 6;
    const int lane = tid & 63;
    const int q    = lane >> 4;
    const int l15  = lane & 15;
    const int wbase = blockIdx.x*64 + wid*32;
    const int wtile = blockIdx.x*2 + wid;

    const int e0 = wbase + l15, e1 = e0 + 16;
    const int s0 = sp16[e0], s1 = sp16[e1];

    const int t2n = tile2node[wtile];
    const int wv = rowstart[t2n + 1 + l15];
    int seg0 = 0, seg1 = 0;
    #pragma unroll
    for (int i = 0; i < 16; ++i) {
        const int wi = __shfl(wv, i);
        seg0 += (e0 >= wi);
        seg1 += (e1 >= wi);
    }
    const int r0 = t2n + seg0, r1 = t2n + seg1;

    int sgrow[2][4];
    #pragma unroll
    for (int r = 0; r < 4; ++r) {
        sgrow[0][r] = __shfl(seg0, 4*q + r);
        sgrow[1][r] = __shfl(seg1, 4*q + r);
    }
    const int segA = __shfl(seg0, 0);
    const int segB = __shfl(seg1, 15);

    const float cdx0 = outv[s0*6+0]-outv[r0*6+0], cdy0 = outv[s0*6+1]-outv[r0*6+1], cdz0 = outv[s0*6+2]-outv[r0*6+2];
    const float cdx1 = outv[s1*6+0]-outv[r1*6+0], cdy1 = outv[s1*6+1]-outv[r1*6+1], cdz1 = outv[s1*6+2]-outv[r1*6+2];
    const float rad0 = cdx0*cdx0+cdy0*cdy0+cdz0*cdz0;
    const float rad1 = cdx1*cdx1+cdy1*cdy1+cdz1*cdz1;

    f32x4 acc[2][4];

    // ---- acc init from R (recv half + b1), fp32 exact ----
    if (segB == segA) {
        const int rn = t2n + segA;
        #pragma unroll
        for (int t = 0; t < 4; ++t) {
            const float rv = R[(size_t)rn*64 + 16*t + l15];
            #pragma unroll
            for (int mu = 0; mu < 2; ++mu)
                #pragma unroll
                for (int r = 0; r < 4; ++r) acc[mu][t][r] = rv;
        }
    } else {
        #pragma unroll
        for (int mu = 0; mu < 2; ++mu)
            #pragma unroll
            for (int r = 0; r < 4; ++r) {
                const size_t ro = (size_t)(t2n + sgrow[mu][r])*64;
                #pragma unroll
                for (int t = 0; t < 4; ++t)
                    acc[mu][t][r] = R[ro + 16*t + l15];
            }
    }

    // ---- GEMM1 (send half only, K=64) ----
    #pragma unroll
    for (int kc = 0; kc < 2; ++kc) {
        const int off = kc*32 + q*8;
        const size_t o0 = (size_t)s0*64 + off;
        const size_t o1 = (size_t)s1*64 + off;
        bf16x8 a0h = ld8(hbh + o0), a0l = ld8(hbl + o0);
        bf16x8 a1h = ld8(hbh + o1), a1l = ld8(hbl + o1);
        #pragma unroll
        for (int t = 0; t < 4; ++t) {
            const int wo = (16*t + l15)*128 + off;
            bf16x8 bh = ld8(w1th + wo), bl = ld8(w1tl + wo);
            mfma3(acc[0][t], a0h, a0l, bh, bl);
            mfma3(acc[1][t], a1h, a1l, bh, bl);
        }
    }

    // radial column (fp32 exact)
    float rsh0[4], rsh1[4];
    #pragma unroll
    for (int r = 0; r < 4; ++r) {
        rsh0[r] = __shfl(rad0, 4*q + r);
        rsh1[r] = __shfl(rad1, 4*q + r);
    }
    #pragma unroll
    for (int t = 0; t < 4; ++t) {
        const float wl = ew1[128*64 + 16*t + l15];
        #pragma unroll
        for (int r = 0; r < 4; ++r) {
            acc[0][t][r] += rsh0[r]*wl;
            acc[1][t][r] += rsh1[r]*wl;
        }
    }

    // t1 = silu -> per-wave LDS hi/lo tiles (C->A layout)
    us* Th = tileh[wid];
    us* Tl = tilel[wid];
    #pragma unroll
    for (int mu = 0; mu < 2; ++mu)
        #pragma unroll
        for (int t = 0; t < 4; ++t)
            #pragma unroll
            for (int r = 0; r < 4; ++r) {
                us hi, lo; split2f(silu_f(acc[mu][t][r]), hi, lo);
                const int ti = (mu*16 + 4*q + r)*TSTRIDE + 16*t + l15;
                Th[ti] = hi; Tl[ti] = lo;
            }
    __asm__ volatile("s_waitcnt lgkmcnt(0)" ::: "memory");

    // ---- GEMM2: t1 @ W2 ----
    #pragma unroll
    for (int mu = 0; mu < 2; ++mu)
        #pragma unroll
        for (int t = 0; t < 4; ++t) acc[mu][t] = (f32x4){0.f,0.f,0.f,0.f};
    #pragma unroll
    for (int kc = 0; kc < 2; ++kc) {
        const int t0 = l15*TSTRIDE + kc*32 + q*8;
        const int t1i = (16+l15)*TSTRIDE + kc*32 + q*8;
        bf16x8 a0h = ld8(Th + t0),  a0l = ld8(Tl + t0);
        bf16x8 a1h = ld8(Th + t1i), a1l = ld8(Tl + t1i);
        #pragma unroll
        for (int t = 0; t < 4; ++t) {
            const int wo = (16*t + l15)*64 + kc*32 + q*8;
            bf16x8 bh = ld8(w2th + wo), bl = ld8(w2tl + wo);
            mfma3(acc[0][t], a0h, a0l, bh, bl);
            mfma3(acc[1][t], a1h, a1l, bh, bl);
        }
    }

    // ef = silu(acc + b2) -> regs (fp32) and tiles (hi/lo)
    float ef[2][4][4];
    #pragma unroll
    for (int t = 0; t < 4; ++t) {
        const float bb = eb2[16*t + l15];
        #pragma unroll
        for (int mu = 0; mu < 2; ++mu)
            #pragma unroll
            for (int r = 0; r < 4; ++r)
                ef[mu][t][r] = silu_f(acc[mu][t][r] + bb);
    }
    __asm__ volatile("s_waitcnt lgkmcnt(0)" ::: "memory");
    #pragma unroll
    for (int mu = 0; mu < 2; ++mu)
        #pragma unroll
        for (int t = 0; t < 4; ++t)
            #pragma unroll
            for (int r = 0; r < 4; ++r) {
                us hi, lo; split2f(ef[mu][t][r], hi, lo);
                const int ti = (mu*16 + 4*q + r)*TSTRIDE + 16*t + l15;
                Th[ti] = hi; Tl[ti] = lo;
            }
    __asm__ volatile("s_waitcnt lgkmcnt(0)" ::: "memory");

    // ---- GEMM3: ef @ CW1 ----
    #pragma unroll
    for (int mu = 0; mu < 2; ++mu)
        #pragma unroll
        for (int t = 0; t < 4; ++t) acc[mu][t] = (f32x4){0.f,0.f,0.f,0.f};
    #pragma unroll
    for (int kc = 0; kc < 2; ++kc) {
        const int t0 = l15*TSTRIDE + kc*32 + q*8;
        const int t1i = (16+l15)*TSTRIDE + kc*32 + q*8;
        bf16x8 a0h = ld8(Th + t0),  a0l = ld8(Tl + t0);
        bf16x8 a1h = ld8(Th + t1i), a1l = ld8(Tl + t1i);
        #pragma unroll
        for (int t = 0; t < 4; ++t) {
            const int wo = (16*t + l15)*64 + kc*32 + q*8;
            bf16x8 bh = ld8(cw1th + wo), bl = ld8(cw1tl + wo);
            mfma3(acc[0][t], a0h, a0l, bh, bl);
            mfma3(acc[1][t], a1h, a1l, bh, bl);
        }
    }

    // ---- GEMM4: cm = silu(acc + cb1) @ CWo; reduce across l15 ----
    float cm0[4] = {0.f,0.f,0.f,0.f}, cm1[4] = {0.f,0.f,0.f,0.f};
    #pragma unroll
    for (int t = 0; t < 4; ++t) {
        const int col = 16*t + l15;
        const float cb = cb1[col];
        const float co = cwo[col];
        #pragma unroll
        for (int r = 0; r < 4; ++r) {
            cm0[r] += silu_f(acc[0][t][r] + cb) * co;
            cm1[r] += silu_f(acc[1][t][r] + cb) * co;
        }
    }
    #pragma unroll
    for (int m = 1; m <= 8; m <<= 1)
        #pragma unroll
        for (int r = 0; r < 4; ++r) {
            cm0[r] += __shfl_xor(cm0[r], m);
            cm1[r] += __shfl_xor(cm1[r], m);
        }

    // ---- trans values ----
    float tv[2][4];
    #pragma unroll
    for (int mu = 0; mu < 2; ++mu)
        #pragma unroll
        for (int r = 0; r < 4; ++r) {
            const float cxv = __shfl(mu ? cdx1 : cdx0, 4*q + r);
            const float cyv = __shfl(mu ? cdy1 : cdy0, 4*q + r);
            const float czv = __shfl(mu ? cdz1 : cdz0, 4*q + r);
            const float cmv = mu ? cm1[r] : cm0[r];
            const float sel = (l15 == 0) ? cxv : (l15 == 1) ? cyv : czv;
            tv[mu][r] = (l15 < 3) ? fminf(fmaxf(sel*cmv, -100.f), 100.f) : 0.f;
        }

    if (segB == segA) {
        float s4[4], trT = 0.f;
        #pragma unroll
        for (int t = 0; t < 4; ++t) {
            float v = 0.f;
            #pragma unroll
            for (int mu = 0; mu < 2; ++mu)
                #pragma unroll
                for (int r = 0; r < 4; ++r) v += ef[mu][t][r];
            v += __shfl_xor(v, 16);
            v += __shfl_xor(v, 32);
            s4[t] = v;
        }
        #pragma unroll
        for (int mu = 0; mu < 2; ++mu)
            #pragma unroll
            for (int r = 0; r < 4; ++r) trT += tv[mu][r];
        trT += __shfl_xor(trT, 16);
        trT += __shfl_xor(trT, 32);
        const int rn = t2n + segA;
        if (q == 0) {
            #pragma unroll
            for (int t = 0; t < 4; ++t)
                atomicAdd(&aggs[(size_t)rn*64 + 16*t + l15], s4[t]);
            if (l15 < 3) atomicAdd(&aggm[rn*3 + l15], trT);
        }
    } else if (segB == segA + 1) {
        float sA[4] = {0,0,0,0}, sB[4] = {0,0,0,0};
        float trA = 0.f, trB = 0.f;
        #pragma unroll
        for (int mu = 0; mu < 2; ++mu)
            #pragma unroll
            for (int r = 0; r < 4; ++r) {
                const bool isA = (sgrow[mu][r] == segA);
                #pragma unroll
                for (int t = 0; t < 4; ++t) {
                    const float v = ef[mu][t][r];
                    sA[t] += isA ? v : 0.f;
                    sB[t] += isA ? 0.f : v;
                }
                const float tvv = tv[mu][r];
                trA += isA ? tvv : 0.f;
                trB += isA ? 0.f : tvv;
            }
        #pragma unroll
        for (int t = 0; t < 4; ++t) {
            sA[t] += __shfl_xor(sA[t], 16); sA[t] += __shfl_xor(sA[t], 32);
            sB[t] += __shfl_xor(sB[t], 16); sB[t] += __shfl_xor(sB[t], 32);
        }
        trA += __shfl_xor(trA, 16); trA += __shfl_xor(trA, 32);
        trB += __shfl_xor(trB, 16); trB += __shfl_xor(trB, 32);
        const int rnA = t2n + segA, rnB = rnA + 1;
        if (q == 0) {
            #pragma unroll
            for (int t = 0; t < 4; ++t) {
                atomicAdd(&aggs[(size_t)rnA*64 + 16*t + l15], sA[t]);
                atomicAdd(&aggs[(size_t)rnB*64 + 16*t + l15], sB[t]);
            }
            if (l15 < 3) {
                atomicAdd(&aggm[rnA*3 + l15], trA);
                atomicAdd(&aggm[rnB*3 + l15], trB);
            }
        }
    } else {
        #pragma unroll
        for (int mu = 0; mu < 2; ++mu)
            #pragma unroll
            for (int r = 0; r < 4; ++r) {
                const int ren = t2n + sgrow[mu][r];
                #pragma unroll
                for (int t = 0; t < 4; ++t)
                    atomicAdd(&aggs[(size_t)ren*64 + 16*t + l15], ef[mu][t][r]);
                if (l15 < 3) atomicAdd(&aggm[ren*3 + l15], tv[mu][r]);
            }
    }
}

// ---------------- node kernel: 4-way ILP GEMVs + fused next-layer R (R14-proven) ----------------
__launch_bounds__(256, 4)
__global__ void k_node(float* __restrict__ aggs, float* __restrict__ aggm,
                       const int* __restrict__ rowstart,
                       const float* __restrict__ VW1, const float* __restrict__ vb1,
                       const float* __restrict__ VW2, const float* __restrict__ vb2,
                       const float* __restrict__ NW1, const float* __restrict__ nb1,
                       const float* __restrict__ NW2, const float* __restrict__ nb2,
                       float* __restrict__ outv,
                       us* __restrict__ hbh, us* __restrict__ hbl,
                       const float* __restrict__ EW1n,
                       const float* __restrict__ eb1n,
                       float* __restrict__ R, int doR) {
    __shared__ float hs[4][64], as[4][64], tt[4][64];
    const int tid = threadIdx.x;
    const int nn = tid >> 6, f = tid & 63;
    const int n = blockIdx.x*4 + nn;
    float hv = b2f(hbh[n*64+f]) + b2f(hbl[n*64+f]);
    hs[nn][f] = hv;
    as[nn][f] = aggs[n*64+f];
    aggs[n*64+f] = 0.f;
    __syncthreads();

    float p0, p1, p2, p3;
    p0 = p1 = p2 = p3 = 0.f;
    for (int k = 0; k < 64; k += 4) {
        p0 += hs[nn][k+0] * VW1[(k+0)*64+f];
        p1 += hs[nn][k+1] * VW1[(k+1)*64+f];
        p2 += hs[nn][k+2] * VW1[(k+2)*64+f];
        p3 += hs[nn][k+3] * VW1[(k+3)*64+f];
    }
    float a1 = vb1[f] + (p0+p1) + (p2+p3);
    float p = silu_f(a1) * VW2[f];
    #pragma unroll
    for (int o = 32; o > 0; o >>= 1) p += __shfl_down(p, o);
    float vgate = __shfl(p, 0) + vb2[0];

    if (f < 3) {
        float icnt = 1.0f / fmaxf((float)(rowstart[n+1] - rowstart[n]), 1.0f);
        float nv = aggm[n*3+f]*icnt + vgate*outv[n*6+3+f];
        aggm[n*3+f] = 0.f;
        outv[n*6+3+f] = nv;
        outv[n*6+f]  += nv;
    }

    p0 = p1 = p2 = p3 = 0.f;
    for (int k = 0; k < 64; k += 4) {
        p0 += hs[nn][k+0]*NW1[(k+0)*64+f] + as[nn][k+0]*NW1[(64+k+0)*64+f];
        p1 += hs[nn][k+1]*NW1[(k+1)*64+f] + as[nn][k+1]*NW1[(64+k+1)*64+f];
        p2 += hs[nn][k+2]*NW1[(k+2)*64+f] + as[nn][k+2]*NW1[(64+k+2)*64+f];
        p3 += hs[nn][k+3]*NW1[(k+3)*64+f] + as[nn][k+3]*NW1[(64+k+3)*64+f];
    }
    float b = nb1[f] + (p0+p1) + (p2+p3);
    __syncthreads();
    tt[nn][f] = silu_f(b);
    __syncthreads();
    p0 = p1 = p2 = p3 = 0.f;
    for (int k = 0; k < 64; k += 4) {
        p0 += tt[nn][k+0]*NW2[(k+0)*64+f];
        p1 += tt[nn][k+1]*NW2[(k+1)*64+f];
        p2 += tt[nn][k+2]*NW2[(k+2)*64+f];
        p3 += tt[nn][k+3]*NW2[(k+3)*64+f];
    }
    float o = nb2[f] + hv + (p0+p1) + (p2+p3);
    us hi, lo; split2r(o, hi, lo);
    hbh[n*64+f] = hi; hbl[n*64+f] = lo;

    if (doR) {
        hs[nn][f] = o;
        __syncthreads();
        p0 = p1 = p2 = p3 = 0.f;
        for (int k = 0; k < 64; k += 4) {
            p0 += hs[nn][k+0] * EW1n[(64+k+0)*64 + f];
            p1 += hs[nn][k+1] * EW1n[(64+k+1)*64 + f];
            p2 += hs[nn][k+2] * EW1n[(64+k+2)*64 + f];
            p3 += hs[nn][k+3] * EW1n[(64+k+3)*64 + f];
        }
        R[(size_t)n*64+f] = eb1n[f] + (p0+p1) + (p2+p3);
    }
}

extern "C" void kernel_launch(void* const* d_in, const int* in_sizes, int n_in,
                              void* d_out, int out_size, void* d_ws, size_t ws_size,
                              hipStream_t stream) {
    const float* inp   = (const float*)d_in[0];
    const int*   send  = (const int*)d_in[2];
    const int*   recv  = (const int*)d_in[3];
    const float* emb_w = (const float*)d_in[4];
    const float* emb_b = (const float*)d_in[5];
    const float* ew1   = (const float*)d_in[6];
    const float* eb1   = (const float*)d_in[7];
    const float* ew2   = (const float*)d_in[8];
    const float* eb2   = (const float*)d_in[9];
    const float* nw1   = (const float*)d_in[10];
    const float* nb1   = (const float*)d_in[11];
    const float* nw2   = (const float*)d_in[12];
    const float* nb2   = (const float*)d_in[13];
    const float* cw1   = (const float*)d_in[14];
    const float* cb1   = (const float*)d_in[15];
    const float* cwo   = (const float*)d_in[16];
    const float* vw1   = (const float*)d_in[17];
    const float* vb1   = (const float*)d_in[18];
    const float* vw2   = (const float*)d_in[19];
    const float* vb2   = (const float*)d_in[20];

    float* outv = (float*)d_out;

    // ws layout — ~18.66 MB (R12/R13-proven envelope)
    float* ws        = (float*)d_ws;
    float* aggs      = ws;
    float* aggm      = aggs + (size_t)N_NODES*64;
    int*   rowstart  = (int*)(aggm + N_NODES*3);
    int*   tile2node = rowstart + (N_NODES+20);
    us*    hbh       = (us*)(tile2node + NTILE);
    us*    hbl       = hbh + (size_t)N_NODES*64;
    us*    sp16      = hbl + (size_t)N_NODES*64;
    us*    w1th      = sp16 + N_EDGES;
    us*    w1tl      = w1th + 4*8192;
    us*    w2th      = w1tl + 4*8192;
    us*    w2tl      = w2th + 4*4096;
    us*    cw1th     = w2tl + 4*4096;
    us*    cw1tl     = cw1th + 4*4096;
    float* R         = (float*)(cw1tl + 4*4096);
    int*   counts    = (int*)aggs;
    int*   cursor    = counts + N_NODES;

    hipMemsetAsync(counts, 0, N_NODES*sizeof(int), stream);
    k_init<<<(N_NODES*64)/256, 256, 0, stream>>>(inp, emb_w, emb_b, outv, hbh, hbl);
    k_cnt<<<(N_EDGES+255)/256, 256, 0, stream>>>(recv, counts);
    k_scan<<<1, 256, 0, stream>>>(counts, rowstart, cursor, tile2node);
    k_scatter<<<(N_EDGES+255)/256, 256, 0, stream>>>(send, recv, cursor, sp16);
    k_prepw<<<256, 256, 0, stream>>>(ew1, ew2, cw1, w1th, w1tl, w2th, w2tl, cw1th, cw1tl);
    hipMemsetAsync(aggs, 0, (size_t)N_NODES*67*sizeof(float), stream);
    k_recv<<<N_NODES/4, 256, 0, stream>>>(hbh, hbl, ew1, eb1, R);

    for (int l = 0; l < NLAYERS; ++l) {
        k_edge<<<N_EDGES/64, 128, 0, stream>>>(sp16, rowstart, tile2node, hbh, hbl, outv, R,
            w1th + l*8192, w1tl + l*8192,
            w2th + l*4096, w2tl + l*4096,
            cw1th + l*4096, cw1tl + l*4096,
            ew1 + (size_t)l*129*64, eb2 + l*64,
            cb1 + l*64, cwo + l*64,
            aggs, aggm);
        const int doR = (l < NLAYERS-1);
        k_node<<<N_NODES/4, 256, 0, stream>>>(aggs, aggm, rowstart,
            vw1 + (size_t)l*64*64, vb1 + l*64, vw2 + l*64, vb2 + l,
            nw1 + (size_t)l*128*64, nb1 + l*64,
            nw2 + (size_t)l*64*64,  nb2 + l*64,
            outv, hbh, hbl,
            ew1 + (size_t)(l+1 < NLAYERS ? l+1 : l)*129*64,
            eb1 + (l+1 < NLAYERS ? l+1 : l)*64,
            R, doR);
    }
}